// Round 16
// baseline (262.817 us; speedup 1.0000x reference)
//
#include <hip/hip_runtime.h>

// Light-field per-pixel 9x9 filter, R16.
// out[b,s,o,h,w] = clip(sum_{i,ky,kx} lf[b,s,i,3h-3+ky,3w-3+kx] * W[s,o,i,h,w,81] + bias, 0, 1)
//
// R11-R15 bracket: LDS-staged weights plateau at 100us (78% achievable BW);
// the stage->drain->compute barrier structure is the residual. R16: NO LDS,
// NO barriers. Each thread reads its own contiguous 9-float weight row as
// 2xfloat4+1 (4B-aligned); wave = (wl:16 x b:4) so b-lanes broadcast-coalesce
// (~16 lines/instr, each weight line fetched once). Waves free-run; HBM issue
// continuous. lf path = R9's vectorized row + shift-select edges.

#define ST 9
#define INC 3
#define OUTC 3
#define OHH 128
#define OWW 128
#define KDIM 9
#define KK 81
#define HH 384
#define WW 384
#define HWSZ (HH*WW)          // 147456

typedef float f32x4 __attribute__((ext_vector_type(4)));
struct __attribute__((packed, aligned(4))) U4 { f32x4 v; };  // align-4 vector load

__global__ __launch_bounds__(128) void lf_filter_kernel(
    const float* __restrict__ lf, const float* __restrict__ wts,
    const float* __restrict__ bias, float* __restrict__ out)
{
  const int t   = threadIdx.x;
  const int wl  = t & 15;          // w lane within 16-group
  const int b   = (t >> 4) & 3;    // batch (4-way weight-line sharing in wave)
  const int wh  = t >> 6;          // which 16-group (2 waves per block)
  const int bid = blockIdx.x;
  const int wg  = bid & 3;         // w group of 32
  const int h   = (bid >> 2) & 127;
  const int s   = bid >> 9;
  const int w   = wg*32 + wh*16 + wl;
  const int xbase = 3*w - 3;
  const int ybase = 3*h - 3;

  // clamped vector-load base + edge shift (nonzero only for w=0 / w=127)
  const int  base  = xbase < 0 ? 0 : (xbase > WW-KDIM ? WW-KDIM : xbase);
  const bool s_neg = (xbase < base);
  const bool s_pos = (xbase > base);

  const float* lfb  = lf + (size_t)(b*ST + s)*INC*HWSZ;
  const size_t wofs = (size_t)w*KK;   // per-thread weight row base (floats)

  float acc[OUTC] = {0.f, 0.f, 0.f};

  #pragma unroll 1
  for (int i = 0; i < INC; ++i) {
    const float* lfr = lfb + (size_t)i*HWSZ;
    #pragma unroll 1
    for (int ky = 0; ky < KDIM; ++ky) {
      const int y = ybase + ky;            // block-uniform -> scalar branch
      if ((unsigned)y < (unsigned)HH) {
        // ---- 9-float lf row, vectorized + shift-select edges ----
        const float* rp = lfr + (size_t)y*WW + base;
        const f32x4 va = reinterpret_cast<const U4*>(rp)->v;
        const f32x4 vb = reinterpret_cast<const U4*>(rp + 4)->v;
        const float rc = rp[8];
        const float raw9[KDIM] = {va.x, va.y, va.z, va.w, vb.x, vb.y, vb.z, vb.w, rc};
        float lv[KDIM];
        #pragma unroll
        for (int kx = 0; kx < KDIM; ++kx) {
          const float nv = (kx >= 3) ? raw9[kx-3] : 0.f;
          const float pv = (kx <= 5) ? raw9[kx+3] : 0.f;
          lv[kx] = s_neg ? nv : (s_pos ? pv : raw9[kx]);
        }
        // ---- 3 o's: contiguous 9-float weight rows straight from global ----
        #pragma unroll
        for (int o = 0; o < OUTC; ++o) {
          const float* wr = wts + ((size_t)(((s*OUTC + o)*INC + i)*OHH + h))*OWW*KK
                              + wofs + ky*KDIM;
          const f32x4 wa = reinterpret_cast<const U4*>(wr)->v;
          const f32x4 wb2 = reinterpret_cast<const U4*>(wr + 4)->v;
          const float wc = wr[8];
          float a = acc[o];
          a = fmaf(lv[0], wa.x, a);
          a = fmaf(lv[1], wa.y, a);
          a = fmaf(lv[2], wa.z, a);
          a = fmaf(lv[3], wa.w, a);
          a = fmaf(lv[4], wb2.x, a);
          a = fmaf(lv[5], wb2.y, a);
          a = fmaf(lv[6], wb2.z, a);
          a = fmaf(lv[7], wb2.w, a);
          a = fmaf(lv[8], wc, a);
          acc[o] = a;
        }
      }
    }
  }

  // ---- epilogue: bias + clip + coalesced stores ----
  #pragma unroll
  for (int o = 0; o < OUTC; ++o) {
    const float bv = bias[((s*OUTC + o)*OHH + h)*OWW + w];
    float r = acc[o] + bv;
    r = r < 0.f ? 0.f : (r > 1.f ? 1.f : r);
    out[(((size_t)(b*ST + s)*OUTC + o)*OHH + h)*OWW + w] = r;
  }
}

extern "C" void kernel_launch(void* const* d_in, const int* in_sizes, int n_in,
                              void* d_out, int out_size, void* d_ws, size_t ws_size,
                              hipStream_t stream) {
  const float* lf   = (const float*)d_in[0];
  const float* wts  = (const float*)d_in[1];
  const float* bias = (const float*)d_in[2];
  float* out = (float*)d_out;
  dim3 grid(ST * OHH * 4);   // 4608 blocks: (s, h, w-group-of-32)
  dim3 block(128);           // (wl:16) x (b:4) x (w-half:2); no LDS, no barriers
  hipLaunchKernelGGL(lf_filter_kernel, grid, block, 0, stream, lf, wts, bias, out);
}

// Round 17
// 99.963 us; speedup vs baseline: 2.6292x; 2.6292x over previous
//
#include <hip/hip_runtime.h>

// Light-field per-pixel 9x9 filter — FINAL (restore R11, session best: 100.0us).
// out[b,s,o,h,w] = clip(sum_{i,ky,kx} lf[b,s,i,3h-3+ky,3w-3+kx] * W[s,o,i,h,w,81] + bias, 0, 1)
//
// Why this structure won (R0-R16 bracket):
//  - Weights (430MB, streamed once) MUST go through LDS staging via
//    global_load_lds: it consumes each HBM line fully, exactly once
//    (FETCH stays at ~490MB compulsory). Direct-global weight reads thrash
//    L2 (R16: 807MB fetch, 2.6x slower); register staging spills (R3/R5/R6).
//  - 10 small blocks/CU (15.6KB LDS each) statistically desynchronize the
//    per-i stage->drain->compute phases: beats dbuf at equal occupancy (R13),
//    dbuf at half occupancy (R12), 32-wave tiny tiles (R15), persistent (R14).
//  - lf rows: vectorized 2xfloat4+1 from clamped base + branchless shift-select
//    for the 2 edge columns; o-innermost reuses each lf row across 3 outputs.
//  - ky-halved across waves; weight LDS reads lane-stride 81 (conflict-free),
//    4-way b-broadcast free.

#define ST 9
#define INC 3
#define OUTC 3
#define OHH 128
#define OWW 128
#define KDIM 9
#define KK 81
#define HH 384
#define WW 384
#define HWSZ (HH*WW)          // 147456
#define WQ 16                 // w columns per block
#define SLICE (WQ*KK)         // 1296 floats = 5184 B per (s,o,i,h,w-16th)

typedef float f32x4 __attribute__((ext_vector_type(4)));
struct __attribute__((packed, aligned(4))) U4 { f32x4 v; };  // align-4 vector load

__device__ __forceinline__ void gll16(const float* g, float* l) {
  __builtin_amdgcn_global_load_lds((const __attribute__((address_space(1))) void*)g,
                                   (__attribute__((address_space(3))) void*)l, 16, 0, 0);
}

__global__ __launch_bounds__(128) void lf_filter_kernel(
    const float* __restrict__ lf, const float* __restrict__ wts,
    const float* __restrict__ bias, float* __restrict__ out)
{
  __shared__ __align__(16) float ldsW[OUTC][SLICE];   // 15552 B -> 10 blocks/CU

  const int t   = threadIdx.x;
  const int wl  = t & 15;          // w within group
  const int b   = (t >> 4) & 3;    // batch
  const int kh  = t >> 6;          // ky half: 0 -> ky 0..4, 1 -> ky 5..8
  const int bid = blockIdx.x;
  const int wg  = bid & 7;         // w group of 16
  const int h   = (bid >> 3) & 127;
  const int s   = bid >> 10;
  const int w   = wg*WQ + wl;
  const int xbase = 3*w - 3;
  const int ybase = 3*h - 3;

  // clamped vector-load base + edge shift (nonzero only for w=0 / w=127)
  const int  base  = xbase < 0 ? 0 : (xbase > WW-KDIM ? WW-KDIM : xbase);
  const bool s_neg = (xbase < base);
  const bool s_pos = (xbase > base);

  const float* lfb = lf + (size_t)(b*ST + s)*INC*HWSZ;
  const int wu = (t & ~63) * 4;    // wave-uniform LDS dest float offset

  const int ky0 = kh ? 5 : 0;
  const int ky1 = kh ? 9 : 5;

  float acc[OUTC] = {0.f, 0.f, 0.f};

  #pragma unroll 1
  for (int i = 0; i < INC; ++i) {
    __syncthreads();   // all waves done reading ldsW from previous i

    // ---- stage the 3 o-slices (324 float4 each) ----
    #pragma unroll
    for (int o = 0; o < OUTC; ++o) {
      const float* wsrc = wts + ((size_t)(((s*OUTC + o)*INC + i)*OHH + h)*OWW + wg*WQ)*KK;
      float* dst = ldsW[o];
      #pragma unroll
      for (int j = 0; j < 2; ++j)                      // 256 chunks
        gll16(wsrc + (size_t)(j*128 + t)*4, dst + j*512 + wu);
      if (t < 68)                                      // tail chunks 256..323
        gll16(wsrc + (size_t)(256 + t)*4, dst + 1024 + wu);
    }
    __syncthreads();   // drain vmcnt: all 3 slices landed

    // ---- compute this thread's ky range; lf row reused across the 3 o's ----
    const float* lfr = lfb + (size_t)i*HWSZ;
    const int wb = wl*KK;
    #pragma unroll 1
    for (int ky = ky0; ky < ky1; ++ky) {
      const int y = ybase + ky;          // wave-uniform branch
      if ((unsigned)y < (unsigned)HH) {
        const float* rp = lfr + (size_t)y*WW + base;
        const f32x4 va = reinterpret_cast<const U4*>(rp)->v;
        const f32x4 vb = reinterpret_cast<const U4*>(rp + 4)->v;
        const float rc = rp[8];
        const float raw[KDIM] = {va.x, va.y, va.z, va.w, vb.x, vb.y, vb.z, vb.w, rc};
        float lv[KDIM];
        #pragma unroll
        for (int kx = 0; kx < KDIM; ++kx) {
          const float nv = (kx >= 3) ? raw[kx-3] : 0.f;
          const float pv = (kx <= 5) ? raw[kx+3] : 0.f;
          lv[kx] = s_neg ? nv : (s_pos ? pv : raw[kx]);
        }
        #pragma unroll
        for (int o = 0; o < OUTC; ++o) {
          const float* wrow = &ldsW[o][wb + ky*KDIM];   // 17*wl mod 32: conflict-free
          float a = acc[o];
          #pragma unroll
          for (int kx = 0; kx < KDIM; ++kx)
            a = fmaf(lv[kx], wrow[kx], a);
          acc[o] = a;
        }
      }
    }
  }

  // ---- combine ky-halves via LDS (reuse ldsW), then epilogue by kh=0 ----
  float* part = (float*)ldsW;       // 64*3 floats, stride-3: conflict-free
  __syncthreads();                  // everyone done reading weights
  if (kh == 1) {
    const int q = t & 63;
    #pragma unroll
    for (int o = 0; o < OUTC; ++o) part[q*3 + o] = acc[o];
  }
  __syncthreads();
  if (kh == 0) {
    #pragma unroll
    for (int o = 0; o < OUTC; ++o) {
      const float bv = bias[((s*OUTC + o)*OHH + h)*OWW + w];
      float r = acc[o] + part[t*3 + o] + bv;
      r = r < 0.f ? 0.f : (r > 1.f ? 1.f : r);
      out[(((size_t)(b*ST + s)*OUTC + o)*OHH + h)*OWW + w] = r;
    }
  }
}

extern "C" void kernel_launch(void* const* d_in, const int* in_sizes, int n_in,
                              void* d_out, int out_size, void* d_ws, size_t ws_size,
                              hipStream_t stream) {
  const float* lf   = (const float*)d_in[0];
  const float* wts  = (const float*)d_in[1];
  const float* bias = (const float*)d_in[2];
  float* out = (float*)d_out;
  dim3 grid(ST * OHH * 8);   // 9216 blocks: (s, h, w-group)
  dim3 block(128);           // (w:16) x (batch:4) x (ky-half:2)
  hipLaunchKernelGGL(lf_filter_kernel, grid, block, 0, stream, lf, wts, bias, out);
}